// Round 8
// baseline (626.856 us; speedup 1.0000x reference)
//
#include <hip/hip_runtime.h>

// Segment-sum via (window, bucket) scatter + L3-windowed pipelined gather.
// H: [N=1.6M, 128] f32, X_node: [N] i32, out: [V=50000, 128] f32.
//
// R7 post-mortem fixes:
//  - cnt/idx metadata loads made wave-uniform via readfirstlane -> s_load
//    (lgkmcnt), so vmcnt carries ONLY row loads + prefetch; index waits no
//    longer drain the prefetch stream.
//  - accumulators: 13 statically-indexed register f2 (no LDS in hot loop).
//  - branchless bucket bodies (clamped row addresses, weight-0 fma for pads;
//    pad loads are duplicate-address L1 hits).
//  - prefetch: PFL=13 compile-time-unrolled global_load_lds, issued LAST in
//    the window body (vmcnt is in-order; nothing waits on it until it has had
//    a full window of slack).

#define D 128
#define BLOCK 256
#define W 16        // row windows (~51.2 MB each)
#define BPW 13      // buckets per wave
#define CAPW 8      // slots per (window, bucket) cell; lambda ~= 2
#define PFL 13      // prefetch float4-loads per lane per window (compile-time)
#define OVF_CAP 650000

typedef float f2 __attribute__((ext_vector_type(2)));

typedef const __attribute__((address_space(1))) char GChar;
typedef __attribute__((address_space(3))) char LChar;

// ---------------- phase 1: windowed scatter ----------------
__global__ void scatter_kernel(const int* __restrict__ idx, int* __restrict__ cnt,
                               int* __restrict__ order, int* __restrict__ ovf_meta,
                               int* __restrict__ ovf, int n, int rpw, int NV) {
    int i = blockIdx.x * blockDim.x + threadIdx.x;
    int stride = gridDim.x * blockDim.x;
    for (; i < n; i += stride) {
        const int v = idx[i];
        const int w = i / rpw;
        const int cell = w * NV + v;
        const int p = atomicAdd(&cnt[cell], 1);
        if (p < CAPW) order[(size_t)cell * CAPW + p] = i;
        else { int q = atomicAdd(ovf_meta, 1); if (q < OVF_CAP) ovf[q] = i; }
    }
}

// ---------------- phase 2: windowed pipelined gather + reduce ----------------
__global__ void __launch_bounds__(BLOCK) reduce_kernel(
        const f2* __restrict__ H2, const char* __restrict__ Hc,
        const int* __restrict__ cnt, const int* __restrict__ order,
        f2* __restrict__ out, int V, int N, int rpw, int NV) {
    __shared__ __align__(16) char pfbuf[1024];   // throwaway prefetch dst

    const int tid  = threadIdx.x;
    const int lane = tid & 63;
    // wave id, forced wave-uniform so metadata addresses scalarize to s_load
    const int wv = __builtin_amdgcn_readfirstlane(blockIdx.x * (BLOCK / 64) + (tid >> 6));
    const int b0 = wv * BPW;

    f2 acc[BPW];
#pragma unroll
    for (int b = 0; b < BPW; ++b) acc[b] = (f2){0.f, 0.f};

    const long h4n = (long)N * 32;            // total float4s in H
    const long w4  = (long)rpw * 32;          // float4s per window
    LChar* ldsdst = (LChar*)&pfbuf[0];        // wave-uniform dest (content unused)

#pragma unroll 1
    for (int w = 0; w < W; ++w) {
        const int cellbase = w * NV + b0;
        // ---- per-bucket: uniform s_load metadata, branchless row loads ----
#pragma unroll
        for (int b = 0; b < BPW; ++b) {
            const int cell = cellbase + b;                 // uniform -> s_load
            int c = cnt[cell];
            c = (c > CAPW) ? CAPW : c;
            const int4* op4 = (const int4*)(order + (size_t)cell * CAPW);
            const int4 q0 = op4[0];                        // uniform -> s_load_dwordx4
            const int4 q1 = op4[1];
            const int e[8] = {q0.x, q0.y, q0.z, q0.w, q1.x, q1.y, q1.z, q1.w};
#pragma unroll
            for (int j = 0; j < 8; ++j) {
                const bool val = (j < c);
                int rid = e[j];
                rid = ((unsigned)rid < (unsigned)N) ? rid : 0;   // poison-safe
                const f2 a = H2[(size_t)rid * 64 + lane];
                const float m = val ? 1.f : 0.f;
                acc[b].x = fmaf(m, a.x, acc[b].x);
                acc[b].y = fmaf(m, a.y, acc[b].y);
            }
        }
        // ---- fire-and-forget stream of window w+1 into L2/L3 (issued LAST) ----
        if (w + 1 < W) {
            const long wb = (long)(w + 1) * w4;
#pragma unroll
            for (int k = 0; k < PFL; ++k) {
                long p = wb + ((long)wv * PFL + k) * 64 + lane;
                p = (p < h4n) ? p : (h4n - 1);
                __builtin_amdgcn_global_load_lds((GChar*)(Hc + p * 16), ldsdst, 16, 0, 0);
            }
        }
    }

#pragma unroll
    for (int b = 0; b < BPW; ++b) {
        const int v = b0 + b;
        if (v < V) out[(size_t)v * 64 + lane] = acc[b];
    }
}

// ---------------- phase 3: overflow fix-up (expected no-op) ----------------
__global__ void ovf_fix_kernel(const f2* __restrict__ H2, const int* __restrict__ idx,
                               const int* __restrict__ ovf_meta, const int* __restrict__ ovf,
                               float* __restrict__ out) {
    int novf = *ovf_meta;
    if (novf <= 0) return;
    novf = (novf > OVF_CAP) ? OVF_CAP : novf;
    const int gid  = blockIdx.x * blockDim.x + threadIdx.x;
    const int wave = gid >> 6;
    const int lane = gid & 63;
    const int nwaves = (gridDim.x * blockDim.x) >> 6;
    for (int o = wave; o < novf; o += nwaves) {
        const int row = ovf[o];
        const int v   = idx[row];
        const f2 a = H2[(size_t)(unsigned)row * 64 + lane];
        atomicAdd(&out[((size_t)v << 7) | ((unsigned)lane << 1)],       a.x);
        atomicAdd(&out[(((size_t)v << 7) | ((unsigned)lane << 1)) + 1], a.y);
    }
}

extern "C" void kernel_launch(void* const* d_in, const int* in_sizes, int n_in,
                              void* d_out, int out_size, void* d_ws, size_t ws_size,
                              hipStream_t stream) {
    const float* H      = (const float*)d_in[0];
    const int*   X_node = (const int*)d_in[1];
    const int N = in_sizes[1];
    const int V = out_size / D;
    float* out = (float*)d_out;

    const int rpw = (N + W - 1) / W;            // rows per window (100,000)
    const int NW  = (V + BPW - 1) / BPW;        // waves (3847)
    const int NV  = NW * BPW;                   // padded bucket count (50,011)

    // ws layout: order[W*NV*CAPW] (16B-aligned first) | cnt[W*NV] | ovf_meta | ovf
    int* order    = (int*)d_ws;
    int* cnt      = order + (size_t)W * NV * CAPW;
    int* ovf_meta = cnt + (size_t)W * NV;
    int* ovf      = ovf_meta + 1;

    hipMemsetAsync(cnt, 0, ((size_t)W * NV + 1) * sizeof(int), stream);

    scatter_kernel<<<2048, BLOCK, 0, stream>>>(X_node, cnt, order, ovf_meta, ovf,
                                               N, rpw, NV);

    const int blocks = (NW + (BLOCK / 64) - 1) / (BLOCK / 64);   // 962
    reduce_kernel<<<blocks, BLOCK, 0, stream>>>(
        (const f2*)H, (const char*)H, cnt, order, (f2*)out, V, N, rpw, NV);

    ovf_fix_kernel<<<16, BLOCK, 0, stream>>>((const f2*)H, X_node, ovf_meta, ovf, out);
}

// Round 9
// 355.680 us; speedup vs baseline: 1.7624x; 1.7624x over previous
//
#include <hip/hip_runtime.h>

// Segment-sum via (window, wave-cell) scatter + L3-windowed pipelined gather.
// H: [N=1.6M, 128] f32, X_node: [N] i32, out: [V=50000, 128] f32.
//
// Mechanism (traffic-verified in R6/R8: reduce FETCH == H exactly once):
// random 512B gathers run ~3 TB/s (DRAM row-activate bound); a sequential
// fire-and-forget stream of window w+1 fills L2/L3 at full DRAM BW while
// window w's rows are gathered out of L3. Correctness never depends on cache
// behavior.
//
// R8 post-mortems folded in:
//  - pad slots load row 0 (L1-hot), NEVER clamped stale indices (R8's 4x
//    random-load amplification on replays).
//  - metadata via readfirstlane-uniform addresses -> s_load (lgkmcnt), so
//    vmcnt carries only row loads + prefetch.
//  - issue order: [meta s_load] [32 row loads] [prefetch w+1] [fma/LDS].
//    Prefetch is NEWER than current rows in the vmcnt FIFO -> row waits never
//    drain it; it retires during the fma phase.
//  - accumulators in LDS (R7-proven, 48 VGPR), wave-private, bl from SGPR:
//    ds addr = uniform base + lane*8 (2-way bank alias = free).

#define D 128
#define BLOCK 256
#define WPB (BLOCK / 64)
#define W 16        // row windows (~51.2 MB each)
#define BPW 13      // buckets per wave
#define CAP 64      // slots per (window, wave) cell; lambda ~= 26
#define PFL 13      // prefetch float4 loads per lane per window
#define OVF_CAP 650000

typedef float f2 __attribute__((ext_vector_type(2)));

typedef const __attribute__((address_space(1))) char GChar;
typedef __attribute__((address_space(3))) char LChar;

// ---------------- phase 1: windowed scatter (+ stream window 0) ----------------
__global__ void scatter_kernel(const int* __restrict__ idx, int* __restrict__ cnt,
                               int* __restrict__ order, int* __restrict__ ovf_meta,
                               int* __restrict__ ovf, int n, int rpw, int NW,
                               const char* __restrict__ Hc, long w4) {
    __shared__ __align__(16) char pfbuf[WPB][1024];
    const int tid = threadIdx.x;
    LChar* ldsdst = (LChar*)&pfbuf[tid >> 6][0];

    // fire-and-forget stream of window 0 into L2/L3 (content never read)
    {
        const long nth = (long)gridDim.x * BLOCK;
        for (long p = (long)blockIdx.x * BLOCK + tid; p < w4; p += nth)
            __builtin_amdgcn_global_load_lds((GChar*)(Hc + p * 16), ldsdst, 16, 0, 0);
    }

    int i = blockIdx.x * blockDim.x + threadIdx.x;
    const int stride = gridDim.x * blockDim.x;
    for (; i < n; i += stride) {
        const int v  = idx[i];
        const int w  = i / rpw;
        const int wv = (unsigned)v / BPW;
        const int bl = v - wv * BPW;
        const int cell = w * NW + wv;
        const int p = atomicAdd(&cnt[cell], 1);
        if (p < CAP) order[(size_t)cell * CAP + p] = (i << 4) | bl;
        else { int q = atomicAdd(ovf_meta, 1); if (q < OVF_CAP) ovf[q] = i; }
    }
}

// ---------------- phase 2: windowed pipelined gather + reduce ----------------
__global__ void __launch_bounds__(BLOCK) reduce_kernel(
        const f2* __restrict__ H2, const char* __restrict__ Hc,
        const int* __restrict__ cnt, const int* __restrict__ order,
        f2* __restrict__ out, int V, int N, int rpw, int NW) {
    __shared__ float accs[WPB][BPW][D];               // 26,624 B
    __shared__ __align__(16) char pfbuf[WPB][1024];

    const int tid  = threadIdx.x;
    const int lane = tid & 63;
    const int wl   = tid >> 6;
    const int wv   = __builtin_amdgcn_readfirstlane(blockIdx.x * WPB + wl);
    const bool active = (wv < NW);
    const int b0 = wv * BPW;

#pragma unroll
    for (int b = 0; b < BPW; ++b) {
        accs[wl][b][2 * lane]     = 0.f;
        accs[wl][b][2 * lane + 1] = 0.f;
    }

    const long h4n = (long)N * 32;            // total float4s in H
    const long w4  = (long)rpw * 32;          // float4s per window
    LChar* ldsdst = (LChar*)&pfbuf[wl][0];

#pragma unroll 1
    for (int w = 0; w < W; ++w) {
        int cc = 0;
        const int4* op4 = nullptr;
        if (active) {
            const int cell = w * NW + wv;                   // uniform -> s_load
            cc = cnt[cell];
            cc = (cc > CAP) ? CAP : cc;
            op4 = (const int4*)(order + (size_t)cell * CAP);
        }

        int e[32]; f2 a[32];
        if (active && cc > 0) {
            int4 q[8];
#pragma unroll
            for (int k = 0; k < 8; ++k) q[k] = op4[k];      // uniform -> s_load_dwordx4
#pragma unroll
            for (int k = 0; k < 8; ++k) {
                e[4 * k + 0] = q[k].x; e[4 * k + 1] = q[k].y;
                e[4 * k + 2] = q[k].z; e[4 * k + 3] = q[k].w;
            }
            // 32 independent row loads; pads load row 0 (valid, L1-hot)
#pragma unroll
            for (int j = 0; j < 32; ++j) {
                const int row = (j < cc) ? (int)((unsigned)e[j] >> 4) : 0;
                a[j] = H2[(size_t)row * 64 + lane];
            }
        }

        // fire-and-forget stream of window w+1 (issued AFTER the row loads:
        // newer in the vmcnt FIFO, so row-data waits never drain it)
        if (w + 1 < W) {
            const long wb = (long)(w + 1) * w4;
#pragma unroll
            for (int k = 0; k < PFL; ++k) {
                long p = wb + ((long)wv * PFL + k) * 64 + lane;
                p = (p < h4n) ? p : (h4n - 1);
                __builtin_amdgcn_global_load_lds((GChar*)(Hc + p * 16), ldsdst, 16, 0, 0);
            }
        }

        if (active && cc > 0) {
            // fma/LDS phase for slots 0..31 (prefetch retires underneath)
#pragma unroll
            for (int j = 0; j < 32; ++j) {
                const bool val = (j < cc);
                const float m  = val ? 1.f : 0.f;
                const int   bl = val ? (e[j] & 15) : 0;
                float* s = &accs[wl][bl][2 * lane];
                s[0] = fmaf(m, a[j].x, s[0]);
                s[1] = fmaf(m, a[j].y, s[1]);
            }
            // tail slots 32..63 (uniform branch, ~10% of cells)
            if (cc > 32) {
                int4 q2[8]; int e2[32]; f2 a2[32];
#pragma unroll
                for (int k = 0; k < 8; ++k) q2[k] = op4[8 + k];
#pragma unroll
                for (int k = 0; k < 8; ++k) {
                    e2[4 * k + 0] = q2[k].x; e2[4 * k + 1] = q2[k].y;
                    e2[4 * k + 2] = q2[k].z; e2[4 * k + 3] = q2[k].w;
                }
#pragma unroll
                for (int j = 0; j < 32; ++j) {
                    const int row = (32 + j < cc) ? (int)((unsigned)e2[j] >> 4) : 0;
                    a2[j] = H2[(size_t)row * 64 + lane];
                }
#pragma unroll
                for (int j = 0; j < 32; ++j) {
                    const bool val = (32 + j < cc);
                    const float m  = val ? 1.f : 0.f;
                    const int   bl = val ? (e2[j] & 15) : 0;
                    float* s = &accs[wl][bl][2 * lane];
                    s[0] = fmaf(m, a2[j].x, s[0]);
                    s[1] = fmaf(m, a2[j].y, s[1]);
                }
            }
        }
    }

    if (active) {
#pragma unroll
        for (int b = 0; b < BPW; ++b) {
            const int v = b0 + b;
            if (v < V) {
                f2 r = {accs[wl][b][2 * lane], accs[wl][b][2 * lane + 1]};
                out[(size_t)v * 64 + lane] = r;
            }
        }
    }
}

// ---------------- phase 3: overflow fix-up (expected no-op) ----------------
__global__ void ovf_fix_kernel(const f2* __restrict__ H2, const int* __restrict__ idx,
                               const int* __restrict__ ovf_meta, const int* __restrict__ ovf,
                               float* __restrict__ out) {
    int novf = *ovf_meta;
    if (novf <= 0) return;
    novf = (novf > OVF_CAP) ? OVF_CAP : novf;
    const int gid  = blockIdx.x * blockDim.x + threadIdx.x;
    const int wave = gid >> 6;
    const int lane = gid & 63;
    const int nwaves = (gridDim.x * blockDim.x) >> 6;
    for (int o = wave; o < novf; o += nwaves) {
        const int row = ovf[o];
        const int v   = idx[row];
        const f2 a = H2[(size_t)(unsigned)row * 64 + lane];
        atomicAdd(&out[((size_t)v << 7) | ((unsigned)lane << 1)],       a.x);
        atomicAdd(&out[(((size_t)v << 7) | ((unsigned)lane << 1)) + 1], a.y);
    }
}

extern "C" void kernel_launch(void* const* d_in, const int* in_sizes, int n_in,
                              void* d_out, int out_size, void* d_ws, size_t ws_size,
                              hipStream_t stream) {
    const float* H      = (const float*)d_in[0];
    const int*   X_node = (const int*)d_in[1];
    const int N = in_sizes[1];
    const int V = out_size / D;
    float* out = (float*)d_out;

    const int rpw = (N + W - 1) / W;            // rows per window (100,000)
    const int NW  = (V + BPW - 1) / BPW;        // wave-cells per window (3847)
    const long w4 = (long)rpw * 32;             // float4s per window

    // ws layout: order[W*NW*CAP] (16B-aligned first) | cnt[W*NW] | ovf_meta | ovf
    int* order    = (int*)d_ws;
    int* cnt      = order + (size_t)W * NW * CAP;
    int* ovf_meta = cnt + (size_t)W * NW;
    int* ovf      = ovf_meta + 1;

    hipMemsetAsync(cnt, 0, ((size_t)W * NW + 1) * sizeof(int), stream);

    scatter_kernel<<<2048, BLOCK, 0, stream>>>(X_node, cnt, order, ovf_meta, ovf,
                                               N, rpw, NW, (const char*)H, w4);

    const int blocks = (NW + WPB - 1) / WPB;    // 962
    reduce_kernel<<<blocks, BLOCK, 0, stream>>>(
        (const f2*)H, (const char*)H, cnt, order, (f2*)out, V, N, rpw, NW);

    ovf_fix_kernel<<<16, BLOCK, 0, stream>>>((const f2*)H, X_node, ovf_meta, ovf, out);
}

// Round 10
// 317.666 us; speedup vs baseline: 1.9733x; 1.1197x over previous
//
#include <hip/hip_runtime.h>

// Segment-sum via direct bucket-table scatter + gather reduce (no float atomics
// in the main path).
// H: [N=1.6M, 128] f32, X_node: [N] i32, out: [V=50000, 128] f32.
//
// R5 structure, reverted to after R6-R9's L3-windowed-prefetch pipeline
// (sequentialize DRAM via fire-and-forget stream + gather out of L3) failed to
// beat it four times (613/335/627/355 vs 312 us) despite FETCH counters
// proving the L3-absorption mechanism worked. The coordination cost (occupancy
// loss, vmcnt coupling, register pressure, wave drift) exceeds the DRAM gain.
//
// Floor arithmetic: reduce = 851 MB at ~3.1 TB/s measured random-512B DRAM
// rate ~= 270 us; scatter ~= 32 us (int-atomic bound); memset/ovf/launch ~= 12.
// Total ~= 312 us == measured. Random-gather roofline.

#define D 128
#define BLOCK 256
#define CAP 128   // per-bucket slot capacity; order table is V*CAP ints

typedef float f2 __attribute__((ext_vector_type(2)));

// ---------------- phase 1: direct scatter ----------------
__global__ void scatter_kernel(const int* __restrict__ idx, int* __restrict__ count,
                               int* __restrict__ order, int* __restrict__ ovf_meta,
                               int* __restrict__ ovf, int n) {
    int i = blockIdx.x * blockDim.x + threadIdx.x;
    int stride = gridDim.x * blockDim.x;
    for (; i < n; i += stride) {
        const int v = idx[i];
        const int p = atomicAdd(&count[v], 1);
        if (p < CAP) {
            order[((unsigned)v << 7) | p] = i;
        } else {
            const int q = atomicAdd(ovf_meta, 1);
            ovf[q] = i;
        }
    }
}

// ---------------- phase 2: gather + reduce ----------------
__global__ void __launch_bounds__(BLOCK) reduce_kernel(const f2* __restrict__ H2,
                                                       const int* __restrict__ count,
                                                       const int* __restrict__ order,
                                                       f2* __restrict__ out, int V) {
    const int gid  = blockIdx.x * blockDim.x + threadIdx.x;
    const int wave = gid >> 6;          // one wavefront per bucket
    if (wave >= V) return;
    const int lane = gid & 63;          // lane owns float2 column `lane`

    int cnt = count[wave];
    if (cnt > CAP) cnt = CAP;           // overflow rows handled by ovf_fix
    const int*  base  = order + ((size_t)wave << 7);
    const int4* base4 = (const int4*)base;

    f2 acc = {0.f, 0.f};
    int g = 0;
    // full groups of 8 rows: 2 int4 index loads + 8 independent 512B row loads
    for (; g + 8 <= cnt; g += 8) {
        const int4 i0 = base4[(g >> 2) + 0];
        const int4 i1 = base4[(g >> 2) + 1];
        const f2 a0 = __builtin_nontemporal_load(H2 + (((unsigned)i0.x << 6) | lane));
        const f2 a1 = __builtin_nontemporal_load(H2 + (((unsigned)i0.y << 6) | lane));
        const f2 a2 = __builtin_nontemporal_load(H2 + (((unsigned)i0.z << 6) | lane));
        const f2 a3 = __builtin_nontemporal_load(H2 + (((unsigned)i0.w << 6) | lane));
        const f2 a4 = __builtin_nontemporal_load(H2 + (((unsigned)i1.x << 6) | lane));
        const f2 a5 = __builtin_nontemporal_load(H2 + (((unsigned)i1.y << 6) | lane));
        const f2 a6 = __builtin_nontemporal_load(H2 + (((unsigned)i1.z << 6) | lane));
        const f2 a7 = __builtin_nontemporal_load(H2 + (((unsigned)i1.w << 6) | lane));
        acc += ((a0 + a1) + (a2 + a3)) + ((a4 + a5) + (a6 + a7));
    }
    // partial group: clamped indices, masked fma — all loads independent,
    // padded lanes re-hit row cnt-1 in L2 (no serial dependent tail).
    if (g < cnt) {
#pragma unroll
        for (int k = 0; k < 7; ++k) {
            const int j  = g + k;
            const int jj = (j < cnt) ? j : (cnt - 1);
            const int n  = base[jj];
            const f2 a = __builtin_nontemporal_load(H2 + (((unsigned)n << 6) | lane));
            const float m = (j < cnt) ? 1.f : 0.f;
            acc.x = fmaf(m, a.x, acc.x);
            acc.y = fmaf(m, a.y, acc.y);
        }
    }
    __builtin_nontemporal_store(acc, out + (((unsigned)wave << 6) | lane));
}

// ---------------- phase 3: overflow fix-up (expected no-op) ----------------
__global__ void ovf_fix_kernel(const f2* __restrict__ H2, const int* __restrict__ idx,
                               const int* __restrict__ ovf_meta, const int* __restrict__ ovf,
                               float* __restrict__ out) {
    const int novf = *ovf_meta;
    if (novf <= 0) return;
    const int gid  = blockIdx.x * blockDim.x + threadIdx.x;
    const int wave = gid >> 6;
    const int lane = gid & 63;
    const int nwaves = (gridDim.x * blockDim.x) >> 6;
    for (int o = wave; o < novf; o += nwaves) {
        const int row = ovf[o];
        const int v   = idx[row];
        const f2 a = H2[(((unsigned)row) << 6) | lane];
        atomicAdd(&out[((unsigned)v << 7) | ((unsigned)lane << 1)],       a.x);
        atomicAdd(&out[(((unsigned)v << 7) | ((unsigned)lane << 1)) + 1], a.y);
    }
}

extern "C" void kernel_launch(void* const* d_in, const int* in_sizes, int n_in,
                              void* d_out, int out_size, void* d_ws, size_t ws_size,
                              hipStream_t stream) {
    const float* H      = (const float*)d_in[0];
    const int*   X_node = (const int*)d_in[1];
    const int N = in_sizes[1];
    const int V = out_size / D;
    float* out = (float*)d_out;

    // ws layout: count[V] | ovf_meta[1] | ovf[N] | order[V*CAP]
    int* count    = (int*)d_ws;
    int* ovf_meta = count + V;
    int* ovf      = ovf_meta + 1;
    int* order    = ovf + N;

    hipMemsetAsync(count, 0, ((size_t)V + 1) * sizeof(int), stream);

    scatter_kernel<<<2048, BLOCK, 0, stream>>>(X_node, count, order, ovf_meta, ovf, N);

    reduce_kernel<<<((size_t)V * 64 + BLOCK - 1) / BLOCK, BLOCK, 0, stream>>>(
        (const f2*)H, count, order, (f2*)out, V);

    ovf_fix_kernel<<<16, BLOCK, 0, stream>>>((const f2*)H, X_node, ovf_meta, ovf, out);
}